// Round 17
// baseline (670.771 us; speedup 1.0000x reference)
//
#include <hip/hip_runtime.h>
#include <cstdint>

#define K_IN   4096
#define N_OUT  4096
#define M_ROWS 16384
#define RANK   8
#define LSCALE 1.0f    // alpha/rank = 8/8
#define NT     64      // K_IN / 64  (BK=64 K-tiles)
#define ROWB   8192    // K_IN * 2 bytes per global row

typedef __attribute__((ext_vector_type(8)))  short short8;
typedef __attribute__((ext_vector_type(4)))  float floatx4;
typedef __attribute__((ext_vector_type(16))) float floatx16;

__device__ __forceinline__ unsigned short f2bf(float f) {
  uint32_t u = __float_as_uint(f);
  u += 0x7FFFu + ((u >> 16) & 1u);
  return (unsigned short)(u >> 16);
}

__global__ __launch_bounds__(256) void fold_w_kernel(
    const float* __restrict__ W, const float* __restrict__ lA,
    const float* __restrict__ lB, unsigned short* __restrict__ Weff) {
  int idx = blockIdx.x * 256 + threadIdx.x;
  int o = idx >> 10;
  int k = (idx & 1023) << 2;
  float4 w = *reinterpret_cast<const float4*>(W + (size_t)o * K_IN + k);
#pragma unroll
  for (int r = 0; r < RANK; ++r) {
    float s = LSCALE * lB[o * RANK + r];
    float4 a = *reinterpret_cast<const float4*>(lA + r * K_IN + k);
    w.x += s * a.x; w.y += s * a.y; w.z += s * a.z; w.w += s * a.w;
  }
  ushort4 p;
  p.x = f2bf(w.x); p.y = f2bf(w.y); p.z = f2bf(w.z); p.w = f2bf(w.w);
  *reinterpret_cast<ushort4*>(Weff + (size_t)o * K_IN + k) = p;
}

__global__ __launch_bounds__(256) void cvt_x_kernel(
    const float* __restrict__ x, unsigned short* __restrict__ xb) {
  size_t i = ((size_t)blockIdx.x * 256 + threadIdx.x) * 8;
  float4 a = *reinterpret_cast<const float4*>(x + i);
  float4 c = *reinterpret_cast<const float4*>(x + i + 4);
  uint4 v;
  v.x = (uint32_t)f2bf(a.x) | ((uint32_t)f2bf(a.y) << 16);
  v.y = (uint32_t)f2bf(a.z) | ((uint32_t)f2bf(a.w) << 16);
  v.z = (uint32_t)f2bf(c.x) | ((uint32_t)f2bf(c.y) << 16);
  v.w = (uint32_t)f2bf(c.z) | ((uint32_t)f2bf(c.w) << 16);
  *reinterpret_cast<uint4*>(xb + i) = v;
}

__device__ __forceinline__ void gload_lds16(const void* g, void* l) {
  __builtin_amdgcn_global_load_lds(
      (const __attribute__((address_space(1))) void*)g,
      (__attribute__((address_space(3))) void*)l, 16, 0, 0);
}

#define BAR() do { asm volatile("" ::: "memory");                         \
    __builtin_amdgcn_s_barrier();                                         \
    asm volatile("" ::: "memory"); } while (0)

#define DSR(DST, ADDR, IMM)                                               \
  asm volatile("ds_read_b128 %0, %1 offset:%2"                            \
               : "=v"(DST) : "v"(ADDR), "i"(IMM))
#define LGKM(N) do {                                                      \
    asm volatile("s_waitcnt lgkmcnt(" #N ")" ::: "memory");               \
    __builtin_amdgcn_sched_barrier(0); } while (0)
#define VMW(N) do {                                                       \
    asm volatile("s_waitcnt vmcnt(" #N ")" ::: "memory");                 \
    __builtin_amdgcn_sched_barrier(0); } while (0)

// ---------------------------------------------------------------------------
// R17 = R16 schedule (best: 471us) + 32x32x16 MFMA + FRAGMENT-MAJOR LDS.
// Why: R16 wall 4418 cyc/tile/CU vs LDS-read floor 2310 and 16x16-MFMA floor
// 2483 (128 MFMA+48 DS issues/SIMD/tile contend). 32x32x16 runs at 2495 TF
// (m119) vs 2176 for 16x16x32 -> floor ~2070 cyc AND halves MFMA issue count.
// 32-row frags break XOR swizzles (>=4-way conflict), so LDS becomes
// FRAGMENT-MAJOR: each 1KB region = one fragment in lane order. One
// gload_lds = one fragment (dest lane-linear; per-lane SOURCE delivers
// row=lane&31, k=(lane>>5)*8). Reads: base + lane*16 + literal — sequential
// per lane = conflict-free by construction, zero swizzle VALU.
// Geometry: 8 waves 2Mx4N, wave tile 128x64; M-frags (32 rows) wr*4+{0..3},
// N-frags wc*2+{0,1}; K-tile 64 = 4 k-steps of 16.
// LDS buf (64KB): A frags [0,32K): f=fm*4+ks at f*1024; B at 32K+g*1024,
// g=fn*4+ks. Read bases: aCur=ldsb+wr*16384+lane*16 (imm=MH*8192+m2*4096+
// ks*1024 <= 15360); bCur=ldsb+32768+wc*8192+lane*16 (imm=NQ*4096+ks*1024).
// Staging: thread stages frag f=h*16+q'*8+wave (A, h=HH) at dest
// buf+HH*16384+q'*8192+tid*16; source = aSrc + (HH*2+q')*64*ROWB + t*128
// where aSrc encodes (wave>>2)*32+(lane&31) row, (wave&3)*32+(lane>>5)*16 k.
// (f>>2 = h*4+q'*2+(wave>>2), f&3 = wave&3 — offsets collapse to +64-row
// multiples, verified.) B identical with Wb/nt.
// Schedule/ledger: BYTE-IDENTICAL to R16 (same read counts 8/4, same stage
// halves, LGKM(12)/(8)/(0), VMW(4) cert at P2, tails VMW(0)/skip, WAR via
// P2-BAR rendezvous — 2x validated).
// C/D layout (m74/m101 HW-verified): col=lane&31,
// row=(reg&3)+8*(reg>>2)+4*(lane>>5). MfmaUtil NOTE: 32x32 has fewer
// busy-cycles per FLOP — the % may drop while perf improves.
// ---------------------------------------------------------------------------
__global__ __launch_bounds__(512, 2) void gemm256_kernel(
    const unsigned short* __restrict__ Xb, const unsigned short* __restrict__ Wb,
    const float* __restrict__ bias, float* __restrict__ out) {
  __shared__ alignas(16) char lds[2 * 65536];   // 128 KiB

  const int tid  = threadIdx.x;
  const int wave = tid >> 6, lane = tid & 63;
  const int wr = wave >> 2, wc = wave & 3;      // 2 (M) x 4 (N) wave grid

  // XCD swizzle: 1024 blocks (%8==0), contiguous 128-tile chunk per XCD
  int bx  = blockIdx.x;
  int sbx = (bx & 7) * 128 + (bx >> 3);
  const int mt = sbx >> 4;   // 0..63
  const int nt = sbx & 15;   // 0..15

  // fragment-major staging sources (per-lane row/k inside the fragment)
  const char* aSrc = (const char*)Xb
      + (size_t)(mt * 256 + (wave >> 2) * 32 + (lane & 31)) * ROWB
      + (wave & 3) * 32 + (lane >> 5) * 16;
  const char* bSrc = (const char*)Wb
      + (size_t)(nt * 256 + (wave >> 2) * 32 + (lane & 31)) * ROWB
      + (wave & 3) * 32 + (lane >> 5) * 16;

#define STAGE_TH(TH, HH) do {                                             \
    char* bufb_ = lds + ((TH) & 1) * 65536;                               \
    if ((HH) < 2) {                                                       \
      const char* s_ = aSrc + (TH) * 128 + (size_t)((HH) * 2) * 524288;   \
      char* d_ = bufb_ + (HH) * 16384 + tid * 16;                         \
      gload_lds16(s_, d_);                                                \
      gload_lds16(s_ + 524288, d_ + 8192);                                \
    } else {                                                              \
      const char* s_ = bSrc + (TH) * 128 + (size_t)(((HH) - 2) * 2) * 524288; \
      char* d_ = bufb_ + 32768 + ((HH) - 2) * 16384 + tid * 16;           \
      gload_lds16(s_, d_);                                                \
      gload_lds16(s_ + 524288, d_ + 8192);                                \
    } } while (0)

  const unsigned ldsb = (unsigned)(unsigned long long)
      (__attribute__((address_space(3))) char*)lds;
  unsigned aCur = ldsb + wr * 16384 + lane * 16;
  unsigned bCur = ldsb + 32768 + wc * 8192 + lane * 16;

#define LOAD_A(DST, MH) do {                                              \
    _Pragma("unroll")                                                     \
    for (int m2 = 0; m2 < 2; ++m2)                                        \
      _Pragma("unroll")                                                   \
      for (int ks = 0; ks < 4; ++ks)                                      \
        DSR(DST[m2 * 4 + ks], aCur,                                       \
            (MH) * 8192 + m2 * 4096 + ks * 1024);                         \
  } while (0)
#define LOAD_B4(DST, NQ) do {                                             \
    _Pragma("unroll")                                                     \
    for (int ks = 0; ks < 4; ++ks)                                        \
      DSR(DST[ks], bCur, (NQ) * 4096 + ks * 1024);                        \
  } while (0)
#define MFMA_Q(MQ, NQ, AF, BF) do {                                       \
    __builtin_amdgcn_s_setprio(1);                                        \
    _Pragma("unroll")                                                     \
    for (int m2 = 0; m2 < 2; ++m2)                                        \
      _Pragma("unroll")                                                   \
      for (int ks = 0; ks < 4; ++ks)                                      \
        acc[(MQ) * 2 + m2][NQ] =                                          \
            __builtin_amdgcn_mfma_f32_32x32x16_bf16(                      \
                AF[m2 * 4 + ks], BF[ks], acc[(MQ) * 2 + m2][NQ], 0, 0, 0);\
    __builtin_amdgcn_s_setprio(0); } while (0)

  floatx16 acc[4][2];
#pragma unroll
  for (int i = 0; i < 4; ++i)
#pragma unroll
    for (int j = 0; j < 2; ++j)
#pragma unroll
      for (int r = 0; r < 16; ++r)
        acc[i][j][r] = 0.f;

  // prologue: tile0 (4 halves) + tile1 h0,h1,h2 = 14 loads; VMW(6) retires
  // tile0 leaving 6 in flight; preload afA(0), bfC(0)
  STAGE_TH(0, 0); STAGE_TH(0, 1); STAGE_TH(0, 2); STAGE_TH(0, 3);
  STAGE_TH(1, 0); STAGE_TH(1, 1); STAGE_TH(1, 2);
  VMW(6);
  BAR();

  short8 afA[8], afB[8], bfC[4], bfD[4];
  LOAD_A(afA, 0);
  LOAD_B4(bfC, 0);

  for (int t = 0; t < NT; ++t) {
    // ---- P0: issue bfD(t), afB(t); stage h3(t+1); MFMA(0,0)
    LOAD_B4(bfD, 1);
    LOAD_A(afB, 1);
    if (t <= NT - 2) STAGE_TH(t + 1, 3);
    LGKM(12);                       // afA + bfC landed
    MFMA_Q(0, 0, afA, bfC);
    BAR();

    // ---- P1: stage h0(t+2); MFMA(0,1)
    if (t <= NT - 3) STAGE_TH(t + 2, 0);
    LGKM(8);                        // bfD landed
    MFMA_Q(0, 1, afA, bfD);
    BAR();

    // ---- P2: stage h1(t+2); MFMA(1,0); counted cert of tile t+1
    if (t <= NT - 3) STAGE_TH(t + 2, 1);
    LGKM(0);                        // afB landed
    MFMA_Q(1, 0, afB, bfC);
    if (t <= NT - 3)      VMW(4);   // retires h3(t+1) exactly; 4 in flight
    else if (t == NT - 2) VMW(0);   // tail: only h3(NT-1) outstanding
    BAR();                          // buf (t+1)&1 certified for all waves

    // ---- P3: issue afA/bfC(t+1); stage h2(t+2); MFMA(1,1)
    if (t <= NT - 2) {
      aCur ^= 65536u; bCur ^= 65536u;
      LOAD_A(afA, 0);
      LOAD_B4(bfC, 0);
    }
    if (t <= NT - 3) STAGE_TH(t + 2, 2);
    __builtin_amdgcn_sched_barrier(0);
    MFMA_Q(1, 1, afB, bfD);
    BAR();
  }
#undef STAGE_TH
#undef LOAD_A
#undef LOAD_B4
#undef MFMA_Q

  // epilogue: 32x32 C/D layout (m74/m101): col=lane&31,
  // row=(reg&3)+8*(reg>>2)+4*(lane>>5)
  const int rowb0 = mt * 256 + wr * 128 + ((lane >> 5) << 2);
  const int colL  = nt * 256 + wc * 64 + (lane & 31);
#pragma unroll
  for (int nf = 0; nf < 2; ++nf) {
    int col = colL + nf * 32;
    float bv = bias[col];
#pragma unroll
    for (int mf = 0; mf < 4; ++mf) {
#pragma unroll
      for (int r = 0; r < 16; ++r) {
        int row = rowb0 + mf * 32 + (r & 3) + ((r >> 2) << 3);
        out[(size_t)row * N_OUT + col] = acc[mf][nf][r] + bv;
      }
    }
  }
}

// self-contained correct fallback (only if ws too small): tiled fp32
__global__ __launch_bounds__(256) void fallback_kernel(
    const float* __restrict__ x, const float* __restrict__ W,
    const float* __restrict__ bias, const float* __restrict__ lA,
    const float* __restrict__ lB, float* __restrict__ out) {
  __shared__ float Xs[64][17];
  __shared__ float Ws[64][17];
  int tid = threadIdx.x;
  int tx = tid & 15, ty = tid >> 4;
  int bm = blockIdx.y * 64, bn = blockIdx.x * 64;
  float acc[4][4] = {};
  for (int k0 = 0; k0 < K_IN; k0 += 16) {
#pragma unroll
    for (int q = 0; q < 4; ++q) {
      int flat = q * 256 + tid;
      int r = flat >> 4, c = flat & 15;
      Xs[r][c] = x[(size_t)(bm + r) * K_IN + k0 + c];
      float w = W[(size_t)(bn + r) * K_IN + k0 + c];
#pragma unroll
      for (int rr = 0; rr < RANK; ++rr)
        w += LSCALE * lB[(bn + r) * RANK + rr] * lA[rr * K_IN + k0 + c];
      Ws[r][c] = w;
    }
    __syncthreads();
#pragma unroll
    for (int kk = 0; kk < 16; ++kk) {
      float av[4], bv[4];
#pragma unroll
      for (int i = 0; i < 4; ++i) av[i] = Xs[ty * 4 + i][kk];
#pragma unroll
      for (int j = 0; j < 4; ++j) bv[j] = Ws[tx * 4 + j][kk];
#pragma unroll
      for (int i = 0; i < 4; ++i)
#pragma unroll
        for (int j = 0; j < 4; ++j) acc[i][j] += av[i] * bv[j];
    }
    __syncthreads();
  }
#pragma unroll
  for (int i = 0; i < 4; ++i)
#pragma unroll
    for (int j = 0; j < 4; ++j)
      out[(size_t)(bm + ty * 4 + i) * N_OUT + bn + tx * 4 + j] =
          acc[i][j] + bias[bn + tx * 4 + j];
}

extern "C" void kernel_launch(void* const* d_in, const int* in_sizes, int n_in,
                              void* d_out, int out_size, void* d_ws, size_t ws_size,
                              hipStream_t stream) {
  const float* x  = (const float*)d_in[0];
  const float* W  = (const float*)d_in[1];
  const float* b  = (const float*)d_in[2];
  const float* lA = (const float*)d_in[3];
  const float* lB = (const float*)d_in[4];
  float* out = (float*)d_out;

  const size_t weff_bytes = (size_t)N_OUT * K_IN * 2;    // 32 MB
  const size_t xb_bytes   = (size_t)M_ROWS * K_IN * 2;   // 128 MB

  if (ws_size >= weff_bytes + xb_bytes) {
    unsigned short* Weff = (unsigned short*)d_ws;
    unsigned short* Xb   = (unsigned short*)((char*)d_ws + weff_bytes);
    fold_w_kernel<<<(int)(((size_t)N_OUT * K_IN / 4) / 256), 256, 0, stream>>>(W, lA, lB, Weff);
    cvt_x_kernel<<<(int)(((size_t)M_ROWS * K_IN / 8) / 256), 256, 0, stream>>>(x, Xb);
    gemm256_kernel<<<(M_ROWS / 256) * (N_OUT / 256), 512, 0, stream>>>(Xb, Weff, b, out);
  } else {
    dim3 grid(N_OUT / 64, M_ROWS / 64);
    fallback_kernel<<<grid, 256, 0, stream>>>(x, W, b, lA, lB, out);
  }
}

// Round 18
// 580.507 us; speedup vs baseline: 1.1555x; 1.1555x over previous
//
#include <hip/hip_runtime.h>
#include <cstdint>

#define K_IN   4096
#define N_OUT  4096
#define M_ROWS 16384
#define RANK   8
#define LSCALE 1.0f    // alpha/rank = 8/8
#define NT     64      // K_IN / 64  (BK=64 K-tiles)
#define ROWB   8192    // K_IN * 2 bytes per global row
#define AHALF  1048576 // 128 rows * ROWB

typedef __attribute__((ext_vector_type(8))) short  short8;
typedef __attribute__((ext_vector_type(4))) float  floatx4;

__device__ __forceinline__ unsigned short f2bf(float f) {
  uint32_t u = __float_as_uint(f);
  u += 0x7FFFu + ((u >> 16) & 1u);
  return (unsigned short)(u >> 16);
}

__global__ __launch_bounds__(256) void fold_w_kernel(
    const float* __restrict__ W, const float* __restrict__ lA,
    const float* __restrict__ lB, unsigned short* __restrict__ Weff) {
  int idx = blockIdx.x * 256 + threadIdx.x;
  int o = idx >> 10;
  int k = (idx & 1023) << 2;
  float4 w = *reinterpret_cast<const float4*>(W + (size_t)o * K_IN + k);
#pragma unroll
  for (int r = 0; r < RANK; ++r) {
    float s = LSCALE * lB[o * RANK + r];
    float4 a = *reinterpret_cast<const float4*>(lA + r * K_IN + k);
    w.x += s * a.x; w.y += s * a.y; w.z += s * a.z; w.w += s * a.w;
  }
  ushort4 p;
  p.x = f2bf(w.x); p.y = f2bf(w.y); p.z = f2bf(w.z); p.w = f2bf(w.w);
  *reinterpret_cast<ushort4*>(Weff + (size_t)o * K_IN + k) = p;
}

__global__ __launch_bounds__(256) void cvt_x_kernel(
    const float* __restrict__ x, unsigned short* __restrict__ xb) {
  size_t i = ((size_t)blockIdx.x * 256 + threadIdx.x) * 8;
  float4 a = *reinterpret_cast<const float4*>(x + i);
  float4 c = *reinterpret_cast<const float4*>(x + i + 4);
  uint4 v;
  v.x = (uint32_t)f2bf(a.x) | ((uint32_t)f2bf(a.y) << 16);
  v.y = (uint32_t)f2bf(a.z) | ((uint32_t)f2bf(a.w) << 16);
  v.z = (uint32_t)f2bf(c.x) | ((uint32_t)f2bf(c.y) << 16);
  v.w = (uint32_t)f2bf(c.z) | ((uint32_t)f2bf(c.w) << 16);
  *reinterpret_cast<uint4*>(xb + i) = v;
}

__device__ __forceinline__ void gload_lds16(const void* g, void* l) {
  __builtin_amdgcn_global_load_lds(
      (const __attribute__((address_space(1))) void*)g,
      (__attribute__((address_space(3))) void*)l, 16, 0, 0);
}

#define BAR() do { asm volatile("" ::: "memory");                         \
    __builtin_amdgcn_s_barrier();                                         \
    asm volatile("" ::: "memory"); } while (0)

#define DSR(DST, ADDR, IMM)                                               \
  asm volatile("ds_read_b128 %0, %1 offset:%2"                            \
               : "=v"(DST) : "v"(ADDR), "i"(IMM))
#define LGKM(N) do {                                                      \
    asm volatile("s_waitcnt lgkmcnt(" #N ")" ::: "memory");               \
    __builtin_amdgcn_sched_barrier(0); } while (0)
#define VMW(N) do {                                                       \
    asm volatile("s_waitcnt vmcnt(" #N ")" ::: "memory");                 \
    __builtin_amdgcn_sched_barrier(0); } while (0)

// ---------------------------------------------------------------------------
// R18 = R16 RESTORED (best: GEMM 471us, MfmaUtil 54, conflicts 0; R17's
// 32x32-MFMA experiment regressed to 600us on accumulator dep-chain ILP and
// is reverted) + one ledger-neutral tweak: each phase's global_load_lds is
// issued BEFORE that phase's ds_read burst (DMA head start; vmcnt and lgkm
// are separate counters and the inter-VMEM instruction order is unchanged,
// so the R16 ledger carries over verbatim).
// Schedule (2x validated): 16x16x32 MFMA, 4 quadrant-phases/K-tile,
// stage 1 half-tile/phase {P0:h3(t+1), P1:h0(t+2), P2:h1(t+2), P3:h2(t+2)},
// counted LGKM(12)/(8)/(0), counted VMW(4) cert at P2 (tail NT-2: VMW(0),
// NT-1: skip), WAR via P2-BAR rendezvous, LDSWZ2 swizzle (conflicts=0.0),
// R11 carry-free base regs, XCD-chunked block swizzle.
// lgkm FIFO at P0(t) entry: [afA8,bfC4] + [bfD4,afB8] = 24:
//   LGKM(12)->afA+bfC; P1 LGKM(8)->bfD; P2 LGKM(0)->afB.
// vmcnt: prologue 14 loads, VMW(6) retires tile0; steady-state queue at
// P2 cert = [h3(t+1)2, h0(t+2)2, h1(t+2)2] -> VMW(4) retires h3(t+1).
// ---------------------------------------------------------------------------
__global__ __launch_bounds__(512, 2) void gemm256_kernel(
    const unsigned short* __restrict__ Xb, const unsigned short* __restrict__ Wb,
    const float* __restrict__ bias, float* __restrict__ out) {
  __shared__ alignas(16) char lds[2 * 65536];   // 128 KiB

  const int tid  = threadIdx.x;
  const int wave = tid >> 6, lane = tid & 63;
  const int wr = wave >> 2, wc = wave & 3;      // 2 (M) x 4 (N) wave grid
  const int l15 = lane & 15, sq = lane >> 4;

  // XCD swizzle: 1024 blocks (%8==0), contiguous 128-tile chunk per XCD
  int bx  = blockIdx.x;
  int sbx = (bx & 7) * 128 + (bx >> 3);
  const int mt = sbx >> 4;   // 0..63
  const int nt = sbx & 15;   // 0..15

  // staging source pre-swizzle (proven R9/R11)
  const int rstg = tid >> 3;
  const int cbst = (((tid & 7) ^ ((tid >> 3) & 7)) << 4);
  const char* aBase = (const char*)Xb + (size_t)(mt * 256 + rstg) * ROWB + cbst;
  const char* bBase = (const char*)Wb + (size_t)(nt * 256 + rstg) * ROWB + cbst;

#define STAGE_TH(TH, HH) do {                                             \
    const char* src_ = ((HH) < 2 ? aBase + (size_t)(HH) * AHALF           \
                                 : bBase + (size_t)((HH) - 2) * AHALF)    \
                       + (TH) * 128;                                      \
    char* dst_ = lds + ((TH) & 1) * 65536 + (HH) * 16384 + tid * 16;      \
    gload_lds16(src_, dst_);                                              \
    gload_lds16(src_ + (size_t)64 * ROWB, dst_ + 8192);                   \
  } while (0)

  // LDS read bases (R11: ks folded inside XOR; imms pure row terms)
  const unsigned ldsb = (unsigned)(unsigned long long)
      (__attribute__((address_space(3))) char*)lds;
  const unsigned X = (unsigned)((l15 & 7) << 4);
  const unsigned aRow = ldsb + wr * 16384 + l15 * 128;
  const unsigned bRow = ldsb + (2 + (wc >> 1)) * 16384 + (wc & 1) * 8192
                        + l15 * 128;
  unsigned aCur0 = aRow + ((0u  + sq * 16) ^ X);
  unsigned aCur1 = aRow + ((64u + sq * 16) ^ X);
  unsigned bCur0 = bRow + ((0u  + sq * 16) ^ X);
  unsigned bCur1 = bRow + ((64u + sq * 16) ^ X);

#define LOAD_A(DST, MQ) do {                                              \
    _Pragma("unroll")                                                     \
    for (int fi = 0; fi < 4; ++fi)                                        \
      DSR(DST[fi],     aCur0, (MQ) * 8192 + fi * 2048);                   \
    _Pragma("unroll")                                                     \
    for (int fi = 0; fi < 4; ++fi)                                        \
      DSR(DST[4 + fi], aCur1, (MQ) * 8192 + fi * 2048);                   \
  } while (0)
#define LOAD_B4(DST, NQ) do {                                             \
    DSR(DST[0], bCur0, (NQ) * 4096);                                      \
    DSR(DST[1], bCur0, (NQ) * 4096 + 2048);                               \
    DSR(DST[2], bCur1, (NQ) * 4096);                                      \
    DSR(DST[3], bCur1, (NQ) * 4096 + 2048);                               \
  } while (0)
#define MFMA_Q(MQ, NQ, AF, BF) do {                                       \
    __builtin_amdgcn_s_setprio(1);                                        \
    _Pragma("unroll")                                                     \
    for (int ks = 0; ks < 2; ++ks)                                        \
      _Pragma("unroll")                                                   \
      for (int fi = 0; fi < 4; ++fi)                                      \
        _Pragma("unroll")                                                 \
        for (int fj = 0; fj < 2; ++fj)                                    \
          acc[(MQ) * 4 + fi][(NQ) * 2 + fj] =                             \
              __builtin_amdgcn_mfma_f32_16x16x32_bf16(                    \
                  AF[ks * 4 + fi], BF[ks * 2 + fj],                       \
                  acc[(MQ) * 4 + fi][(NQ) * 2 + fj], 0, 0, 0);            \
    __builtin_amdgcn_s_setprio(0); } while (0)

  floatx4 acc[8][4];
#pragma unroll
  for (int i = 0; i < 8; ++i)
#pragma unroll
    for (int j = 0; j < 4; ++j)
      acc[i][j] = (floatx4){0.f, 0.f, 0.f, 0.f};

  // prologue: tile0 (4 halves) + tile1 h0,h1,h2 = 14 loads; VMW(6) retires
  // tile0 leaving 6 in flight; preload afA(0), bfC(0)
  STAGE_TH(0, 0); STAGE_TH(0, 1); STAGE_TH(0, 2); STAGE_TH(0, 3);
  STAGE_TH(1, 0); STAGE_TH(1, 1); STAGE_TH(1, 2);
  VMW(6);
  BAR();

  short8 afA[8], afB[8], bfC[4], bfD[4];
  LOAD_A(afA, 0);
  LOAD_B4(bfC, 0);

  for (int t = 0; t < NT; ++t) {
    // ---- P0: stage h3(t+1) [DMA head start]; issue bfD(t), afB(t); MFMA(0,0)
    if (t <= NT - 2) STAGE_TH(t + 1, 3);
    LOAD_B4(bfD, 1);
    LOAD_A(afB, 1);
    LGKM(12);                       // afA + bfC landed
    MFMA_Q(0, 0, afA, bfC);
    BAR();

    // ---- P1: stage h0(t+2); MFMA(0,1)
    if (t <= NT - 3) STAGE_TH(t + 2, 0);
    LGKM(8);                        // bfD landed
    MFMA_Q(0, 1, afA, bfD);
    BAR();

    // ---- P2: stage h1(t+2); MFMA(1,0); counted cert of tile t+1
    if (t <= NT - 3) STAGE_TH(t + 2, 1);
    LGKM(0);                        // afB landed
    MFMA_Q(1, 0, afB, bfC);
    if (t <= NT - 3)      VMW(4);   // retires h3(t+1) exactly; 4 in flight
    else if (t == NT - 2) VMW(0);   // tail: only h3(NT-1) outstanding
    BAR();                          // buf (t+1)&1 certified for all waves

    // ---- P3: stage h2(t+2) [head start]; issue afA/bfC(t+1); MFMA(1,1)
    if (t <= NT - 3) STAGE_TH(t + 2, 2);
    if (t <= NT - 2) {
      aCur0 ^= 65536u; aCur1 ^= 65536u; bCur0 ^= 65536u; bCur1 ^= 65536u;
      LOAD_A(afA, 0);
      LOAD_B4(bfC, 0);
    }
    __builtin_amdgcn_sched_barrier(0);
    MFMA_Q(1, 1, afB, bfD);
    BAR();
  }
#undef STAGE_TH
#undef LOAD_A
#undef LOAD_B4
#undef MFMA_Q

  // epilogue: C/D layout col=lane&15, row=(lane>>4)*4+reg (m89/m91 verified)
  const int row0 = mt * 256 + wr * 128 + sq * 4;
  const int col0 = nt * 256 + wc * 64 + l15;
#pragma unroll
  for (int j = 0; j < 4; ++j) {
    int col = col0 + j * 16;
    float bv = bias[col];
#pragma unroll
    for (int i = 0; i < 8; ++i) {
      int rowb = row0 + i * 16;
#pragma unroll
      for (int rr = 0; rr < 4; ++rr)
        out[(size_t)(rowb + rr) * N_OUT + col] = acc[i][j][rr] + bv;
    }
  }
}

// self-contained correct fallback (only if ws too small): tiled fp32
__global__ __launch_bounds__(256) void fallback_kernel(
    const float* __restrict__ x, const float* __restrict__ W,
    const float* __restrict__ bias, const float* __restrict__ lA,
    const float* __restrict__ lB, float* __restrict__ out) {
  __shared__ float Xs[64][17];
  __shared__ float Ws[64][17];
  int tid = threadIdx.x;
  int tx = tid & 15, ty = tid >> 4;
  int bm = blockIdx.y * 64, bn = blockIdx.x * 64;
  float acc[4][4] = {};
  for (int k0 = 0; k0 < K_IN; k0 += 16) {
#pragma unroll
    for (int q = 0; q < 4; ++q) {
      int flat = q * 256 + tid;
      int r = flat >> 4, c = flat & 15;
      Xs[r][c] = x[(size_t)(bm + r) * K_IN + k0 + c];
      float w = W[(size_t)(bn + r) * K_IN + k0 + c];
#pragma unroll
      for (int rr = 0; rr < RANK; ++rr)
        w += LSCALE * lB[(bn + r) * RANK + rr] * lA[rr * K_IN + k0 + c];
      Ws[r][c] = w;
    }
    __syncthreads();
#pragma unroll
    for (int kk = 0; kk < 16; ++kk) {
      float av[4], bv[4];
#pragma unroll
      for (int i = 0; i < 4; ++i) av[i] = Xs[ty * 4 + i][kk];
#pragma unroll
      for (int j = 0; j < 4; ++j) bv[j] = Ws[tx * 4 + j][kk];
#pragma unroll
      for (int i = 0; i < 4; ++i)
#pragma unroll
        for (int j = 0; j < 4; ++j) acc[i][j] += av[i] * bv[j];
    }
    __syncthreads();
  }
#pragma unroll
  for (int i = 0; i < 4; ++i)
#pragma unroll
    for (int j = 0; j < 4; ++j)
      out[(size_t)(bm + ty * 4 + i) * N_OUT + bn + tx * 4 + j] =
          acc[i][j] + bias[bn + tx * 4 + j];
}

extern "C" void kernel_launch(void* const* d_in, const int* in_sizes, int n_in,
                              void* d_out, int out_size, void* d_ws, size_t ws_size,
                              hipStream_t stream) {
  const float* x  = (const float*)d_in[0];
  const float* W  = (const float*)d_in[1];
  const float* b  = (const float*)d_in[2];
  const float* lA = (const float*)d_in[3];
  const float* lB = (const float*)d_in[4];
  float* out = (float*)d_out;

  const size_t weff_bytes = (size_t)N_OUT * K_IN * 2;    // 32 MB
  const size_t xb_bytes   = (size_t)M_ROWS * K_IN * 2;   // 128 MB

  if (ws_size >= weff_bytes + xb_bytes) {
    unsigned short* Weff = (unsigned short*)d_ws;
    unsigned short* Xb   = (unsigned short*)((char*)d_ws + weff_bytes);
    fold_w_kernel<<<(int)(((size_t)N_OUT * K_IN / 4) / 256), 256, 0, stream>>>(W, lA, lB, Weff);
    cvt_x_kernel<<<(int)(((size_t)M_ROWS * K_IN / 8) / 256), 256, 0, stream>>>(x, Xb);
    gemm256_kernel<<<(M_ROWS / 256) * (N_OUT / 256), 512, 0, stream>>>(Xb, Weff, b, out);
  } else {
    dim3 grid(N_OUT / 64, M_ROWS / 64);
    fallback_kernel<<<grid, 256, 0, stream>>>(x, W, b, lA, lB, out);
  }
}

// Round 19
// 573.072 us; speedup vs baseline: 1.1705x; 1.0130x over previous
//
#include <hip/hip_runtime.h>
#include <cstdint>

#define K_IN   4096
#define N_OUT  4096
#define M_ROWS 16384
#define RANK   8
#define LSCALE 1.0f    // alpha/rank = 8/8
#define NT     64      // K_IN / 64  (BK=64 K-tiles)
#define ROWB   8192    // K_IN * 2 bytes per global row
#define AHALF  1048576 // 128 rows * ROWB

typedef __attribute__((ext_vector_type(8))) short  short8;
typedef __attribute__((ext_vector_type(4))) float  floatx4;

__device__ __forceinline__ unsigned short f2bf(float f) {
  uint32_t u = __float_as_uint(f);
  u += 0x7FFFu + ((u >> 16) & 1u);
  return (unsigned short)(u >> 16);
}

__global__ __launch_bounds__(256) void fold_w_kernel(
    const float* __restrict__ W, const float* __restrict__ lA,
    const float* __restrict__ lB, unsigned short* __restrict__ Weff) {
  int idx = blockIdx.x * 256 + threadIdx.x;
  int o = idx >> 10;
  int k = (idx & 1023) << 2;
  float4 w = *reinterpret_cast<const float4*>(W + (size_t)o * K_IN + k);
#pragma unroll
  for (int r = 0; r < RANK; ++r) {
    float s = LSCALE * lB[o * RANK + r];
    float4 a = *reinterpret_cast<const float4*>(lA + r * K_IN + k);
    w.x += s * a.x; w.y += s * a.y; w.z += s * a.z; w.w += s * a.w;
  }
  ushort4 p;
  p.x = f2bf(w.x); p.y = f2bf(w.y); p.z = f2bf(w.z); p.w = f2bf(w.w);
  *reinterpret_cast<ushort4*>(Weff + (size_t)o * K_IN + k) = p;
}

__global__ __launch_bounds__(256) void cvt_x_kernel(
    const float* __restrict__ x, unsigned short* __restrict__ xb) {
  size_t i = ((size_t)blockIdx.x * 256 + threadIdx.x) * 8;
  float4 a = *reinterpret_cast<const float4*>(x + i);
  float4 c = *reinterpret_cast<const float4*>(x + i + 4);
  uint4 v;
  v.x = (uint32_t)f2bf(a.x) | ((uint32_t)f2bf(a.y) << 16);
  v.y = (uint32_t)f2bf(a.z) | ((uint32_t)f2bf(a.w) << 16);
  v.z = (uint32_t)f2bf(c.x) | ((uint32_t)f2bf(c.y) << 16);
  v.w = (uint32_t)f2bf(c.z) | ((uint32_t)f2bf(c.w) << 16);
  *reinterpret_cast<uint4*>(xb + i) = v;
}

__device__ __forceinline__ void gload_lds16(const void* g, void* l) {
  __builtin_amdgcn_global_load_lds(
      (const __attribute__((address_space(1))) void*)g,
      (__attribute__((address_space(3))) void*)l, 16, 0, 0);
}

#define BAR() do { asm volatile("" ::: "memory");                         \
    __builtin_amdgcn_s_barrier();                                         \
    asm volatile("" ::: "memory"); } while (0)

#define DSR(DST, ADDR, IMM)                                               \
  asm volatile("ds_read_b128 %0, %1 offset:%2"                            \
               : "=v"(DST) : "v"(ADDR), "i"(IMM))
#define LGKM(N) do {                                                      \
    asm volatile("s_waitcnt lgkmcnt(" #N ")" ::: "memory");               \
    __builtin_amdgcn_sched_barrier(0); } while (0)
#define VMW(N) do {                                                       \
    asm volatile("s_waitcnt vmcnt(" #N ")" ::: "memory");                 \
    __builtin_amdgcn_sched_barrier(0); } while (0)

// ---------------------------------------------------------------------------
// R19 = R16 verbatim — the session's measured optimum (GEMM 471us, 1.17 PF,
// MfmaUtil 54%, bank-conflicts 0). Converged after single-lever A/Bs:
// R13 read-spread 570, R14 2-barrier 625, R15 B-direct-to-reg 731,
// R17 32x32-MFMA 600, R18 DMA-hoist 480 (noise) — all regressed or null.
// Structural constraints documented: (1) 256^2/8-wave needs 128 acc VGPRs
// -> combined V+A ~256 -> hard 2 waves/SIMD -> 1 block/CU (no TLP exit);
// (2) wall 4418 cyc/tile/CU vs MFMA-issue floor 2483 + LDS service 2310 —
// the residual overlap gap is the HK fine-interleave, which resisted
// 7 incremental ports; (3) fp8/MX paths fail the 0.114 absmax threshold
// at K=4096 (max-err ~0.29).
// Schedule (3x validated): 16x16x32 MFMA, 4 quadrant-phases/K-tile,
// stage 1 half-tile/phase {P0:h3(t+1), P1:h0(t+2), P2:h1(t+2), P3:h2(t+2)},
// counted LGKM(12)/(8)/(0), counted VMW(4) cert at P2 (tail NT-2: VMW(0),
// NT-1: skip), WAR via P2-BAR rendezvous, LDSWZ2 swizzle (conflicts=0.0),
// R11 carry-free base regs, XCD-chunked block swizzle.
// lgkm FIFO at P0(t) entry: [afA8,bfC4] + [bfD4,afB8] = 24:
//   LGKM(12)->afA+bfC; P1 LGKM(8)->bfD; P2 LGKM(0)->afB.
// vmcnt: prologue 14 loads, VMW(6) retires tile0; steady-state queue at
// P2 cert = [h3(t+1)2, h0(t+2)2, h1(t+2)2] -> VMW(4) retires h3(t+1).
// ---------------------------------------------------------------------------
__global__ __launch_bounds__(512, 2) void gemm256_kernel(
    const unsigned short* __restrict__ Xb, const unsigned short* __restrict__ Wb,
    const float* __restrict__ bias, float* __restrict__ out) {
  __shared__ alignas(16) char lds[2 * 65536];   // 128 KiB

  const int tid  = threadIdx.x;
  const int wave = tid >> 6, lane = tid & 63;
  const int wr = wave >> 2, wc = wave & 3;      // 2 (M) x 4 (N) wave grid
  const int l15 = lane & 15, sq = lane >> 4;

  // XCD swizzle: 1024 blocks (%8==0), contiguous 128-tile chunk per XCD
  int bx  = blockIdx.x;
  int sbx = (bx & 7) * 128 + (bx >> 3);
  const int mt = sbx >> 4;   // 0..63
  const int nt = sbx & 15;   // 0..15

  // staging source pre-swizzle (proven R9/R11)
  const int rstg = tid >> 3;
  const int cbst = (((tid & 7) ^ ((tid >> 3) & 7)) << 4);
  const char* aBase = (const char*)Xb + (size_t)(mt * 256 + rstg) * ROWB + cbst;
  const char* bBase = (const char*)Wb + (size_t)(nt * 256 + rstg) * ROWB + cbst;

#define STAGE_TH(TH, HH) do {                                             \
    const char* src_ = ((HH) < 2 ? aBase + (size_t)(HH) * AHALF           \
                                 : bBase + (size_t)((HH) - 2) * AHALF)    \
                       + (TH) * 128;                                      \
    char* dst_ = lds + ((TH) & 1) * 65536 + (HH) * 16384 + tid * 16;      \
    gload_lds16(src_, dst_);                                              \
    gload_lds16(src_ + (size_t)64 * ROWB, dst_ + 8192);                   \
  } while (0)

  // LDS read bases (R11: ks folded inside XOR; imms pure row terms)
  const unsigned ldsb = (unsigned)(unsigned long long)
      (__attribute__((address_space(3))) char*)lds;
  const unsigned X = (unsigned)((l15 & 7) << 4);
  const unsigned aRow = ldsb + wr * 16384 + l15 * 128;
  const unsigned bRow = ldsb + (2 + (wc >> 1)) * 16384 + (wc & 1) * 8192
                        + l15 * 128;
  unsigned aCur0 = aRow + ((0u  + sq * 16) ^ X);
  unsigned aCur1 = aRow + ((64u + sq * 16) ^ X);
  unsigned bCur0 = bRow + ((0u  + sq * 16) ^ X);
  unsigned bCur1 = bRow + ((64u + sq * 16) ^ X);

#define LOAD_A(DST, MQ) do {                                              \
    _Pragma("unroll")                                                     \
    for (int fi = 0; fi < 4; ++fi)                                        \
      DSR(DST[fi],     aCur0, (MQ) * 8192 + fi * 2048);                   \
    _Pragma("unroll")                                                     \
    for (int fi = 0; fi < 4; ++fi)                                        \
      DSR(DST[4 + fi], aCur1, (MQ) * 8192 + fi * 2048);                   \
  } while (0)
#define LOAD_B4(DST, NQ) do {                                             \
    DSR(DST[0], bCur0, (NQ) * 4096);                                      \
    DSR(DST[1], bCur0, (NQ) * 4096 + 2048);                               \
    DSR(DST[2], bCur1, (NQ) * 4096);                                      \
    DSR(DST[3], bCur1, (NQ) * 4096 + 2048);                               \
  } while (0)
#define MFMA_Q(MQ, NQ, AF, BF) do {                                       \
    __builtin_amdgcn_s_setprio(1);                                        \
    _Pragma("unroll")                                                     \
    for (int ks = 0; ks < 2; ++ks)                                        \
      _Pragma("unroll")                                                   \
      for (int fi = 0; fi < 4; ++fi)                                      \
        _Pragma("unroll")                                                 \
        for (int fj = 0; fj < 2; ++fj)                                    \
          acc[(MQ) * 4 + fi][(NQ) * 2 + fj] =                             \
              __builtin_amdgcn_mfma_f32_16x16x32_bf16(                    \
                  AF[ks * 4 + fi], BF[ks * 2 + fj],                       \
                  acc[(MQ) * 4 + fi][(NQ) * 2 + fj], 0, 0, 0);            \
    __builtin_amdgcn_s_setprio(0); } while (0)

  floatx4 acc[8][4];
#pragma unroll
  for (int i = 0; i < 8; ++i)
#pragma unroll
    for (int j = 0; j < 4; ++j)
      acc[i][j] = (floatx4){0.f, 0.f, 0.f, 0.f};

  // prologue: tile0 (4 halves) + tile1 h0,h1,h2 = 14 loads; VMW(6) retires
  // tile0 leaving 6 in flight; preload afA(0), bfC(0)
  STAGE_TH(0, 0); STAGE_TH(0, 1); STAGE_TH(0, 2); STAGE_TH(0, 3);
  STAGE_TH(1, 0); STAGE_TH(1, 1); STAGE_TH(1, 2);
  VMW(6);
  BAR();

  short8 afA[8], afB[8], bfC[4], bfD[4];
  LOAD_A(afA, 0);
  LOAD_B4(bfC, 0);

  for (int t = 0; t < NT; ++t) {
    // ---- P0: issue bfD(t), afB(t); stage h3(t+1); MFMA(0,0)
    LOAD_B4(bfD, 1);
    LOAD_A(afB, 1);
    if (t <= NT - 2) STAGE_TH(t + 1, 3);
    LGKM(12);                       // afA + bfC landed
    MFMA_Q(0, 0, afA, bfC);
    BAR();

    // ---- P1: stage h0(t+2); MFMA(0,1)
    if (t <= NT - 3) STAGE_TH(t + 2, 0);
    LGKM(8);                        // bfD landed
    MFMA_Q(0, 1, afA, bfD);
    BAR();

    // ---- P2: stage h1(t+2); MFMA(1,0); counted cert of tile t+1
    if (t <= NT - 3) STAGE_TH(t + 2, 1);
    LGKM(0);                        // afB landed
    MFMA_Q(1, 0, afB, bfC);
    if (t <= NT - 3)      VMW(4);   // retires h3(t+1) exactly; 4 in flight
    else if (t == NT - 2) VMW(0);   // tail: only h3(NT-1) outstanding
    BAR();                          // buf (t+1)&1 certified for all waves

    // ---- P3: issue afA/bfC(t+1); stage h2(t+2); MFMA(1,1)
    if (t <= NT - 2) {
      aCur0 ^= 65536u; aCur1 ^= 65536u; bCur0 ^= 65536u; bCur1 ^= 65536u;
      LOAD_A(afA, 0);
      LOAD_B4(bfC, 0);
    }
    if (t <= NT - 3) STAGE_TH(t + 2, 2);
    __builtin_amdgcn_sched_barrier(0);
    MFMA_Q(1, 1, afB, bfD);
    BAR();
  }
#undef STAGE_TH
#undef LOAD_A
#undef LOAD_B4
#undef MFMA_Q

  // epilogue: C/D layout col=lane&15, row=(lane>>4)*4+reg (m89/m91 verified)
  const int row0 = mt * 256 + wr * 128 + sq * 4;
  const int col0 = nt * 256 + wc * 64 + l15;
#pragma unroll
  for (int j = 0; j < 4; ++j) {
    int col = col0 + j * 16;
    float bv = bias[col];
#pragma unroll
    for (int i = 0; i < 8; ++i) {
      int rowb = row0 + i * 16;
#pragma unroll
      for (int rr = 0; rr < 4; ++rr)
        out[(size_t)(rowb + rr) * N_OUT + col] = acc[i][j][rr] + bv;
    }
  }
}

// self-contained correct fallback (only if ws too small): tiled fp32
__global__ __launch_bounds__(256) void fallback_kernel(
    const float* __restrict__ x, const float* __restrict__ W,
    const float* __restrict__ bias, const float* __restrict__ lA,
    const float* __restrict__ lB, float* __restrict__ out) {
  __shared__ float Xs[64][17];
  __shared__ float Ws[64][17];
  int tid = threadIdx.x;
  int tx = tid & 15, ty = tid >> 4;
  int bm = blockIdx.y * 64, bn = blockIdx.x * 64;
  float acc[4][4] = {};
  for (int k0 = 0; k0 < K_IN; k0 += 16) {
#pragma unroll
    for (int q = 0; q < 4; ++q) {
      int flat = q * 256 + tid;
      int r = flat >> 4, c = flat & 15;
      Xs[r][c] = x[(size_t)(bm + r) * K_IN + k0 + c];
      float w = W[(size_t)(bn + r) * K_IN + k0 + c];
#pragma unroll
      for (int rr = 0; rr < RANK; ++rr)
        w += LSCALE * lB[(bn + r) * RANK + rr] * lA[rr * K_IN + k0 + c];
      Ws[r][c] = w;
    }
    __syncthreads();
#pragma unroll
    for (int kk = 0; kk < 16; ++kk) {
      float av[4], bv[4];
#pragma unroll
      for (int i = 0; i < 4; ++i) av[i] = Xs[ty * 4 + i][kk];
#pragma unroll
      for (int j = 0; j < 4; ++j) bv[j] = Ws[tx * 4 + j][kk];
#pragma unroll
      for (int i = 0; i < 4; ++i)
#pragma unroll
        for (int j = 0; j < 4; ++j) acc[i][j] += av[i] * bv[j];
    }
    __syncthreads();
  }
#pragma unroll
  for (int i = 0; i < 4; ++i)
#pragma unroll
    for (int j = 0; j < 4; ++j)
      out[(size_t)(bm + ty * 4 + i) * N_OUT + bn + tx * 4 + j] =
          acc[i][j] + bias[bn + tx * 4 + j];
}

extern "C" void kernel_launch(void* const* d_in, const int* in_sizes, int n_in,
                              void* d_out, int out_size, void* d_ws, size_t ws_size,
                              hipStream_t stream) {
  const float* x  = (const float*)d_in[0];
  const float* W  = (const float*)d_in[1];
  const float* b  = (const float*)d_in[2];
  const float* lA = (const float*)d_in[3];
  const float* lB = (const float*)d_in[4];
  float* out = (float*)d_out;

  const size_t weff_bytes = (size_t)N_OUT * K_IN * 2;    // 32 MB
  const size_t xb_bytes   = (size_t)M_ROWS * K_IN * 2;   // 128 MB

  if (ws_size >= weff_bytes + xb_bytes) {
    unsigned short* Weff = (unsigned short*)d_ws;
    unsigned short* Xb   = (unsigned short*)((char*)d_ws + weff_bytes);
    fold_w_kernel<<<(int)(((size_t)N_OUT * K_IN / 4) / 256), 256, 0, stream>>>(W, lA, lB, Weff);
    cvt_x_kernel<<<(int)(((size_t)M_ROWS * K_IN / 8) / 256), 256, 0, stream>>>(x, Xb);
    gemm256_kernel<<<(M_ROWS / 256) * (N_OUT / 256), 512, 0, stream>>>(Xb, Weff, b, out);
  } else {
    dim3 grid(N_OUT / 64, M_ROWS / 64);
    fallback_kernel<<<grid, 256, 0, stream>>>(x, W, b, lA, lB, out);
  }
}